// Round 1
// baseline (220.996 us; speedup 1.0000x reference)
//
#include <hip/hip_runtime.h>
#include <math.h>

#define B_ 16
#define T_ 24
#define N_ 300
#define E_ 9600
#define H_ 3
#define F_ 8
#define HF_ 24
#define GRUH_ 16
#define OUTB_ 7200   // NUM_AIRPORTS * HORIZON

// ---- monotone float<->uint mapping for atomicMax on floats ----
__device__ __forceinline__ unsigned fkey(float f) {
    unsigned u = __float_as_uint(f);
    return (u & 0x80000000u) ? ~u : (u | 0x80000000u);
}
__device__ __forceinline__ float fdec(unsigned k) {
    unsigned u = (k & 0x80000000u) ? (k & 0x7fffffffu) : ~k;
    return __uint_as_float(u);
}

// ================= Kernel A: EdgeGAT + mean-pool, one block per (b,t) ================
__global__ __launch_bounds__(256) void gat_kernel(
    const float* __restrict__ x, const float* __restrict__ ew,
    const float* __restrict__ Wn, const float* __restrict__ We,
    const float* __restrict__ al, const float* __restrict__ ar,
    const float* __restrict__ ae, const float* __restrict__ gbias,
    const int* __restrict__ src, const int* __restrict__ dst,
    float* __restrict__ gru_in)
{
    __shared__ float xs[N_];
    __shared__ unsigned mKey[N_ * H_];
    __shared__ float den[N_ * H_];
    __shared__ float snum[N_ * H_];
    __shared__ float coef[9];
    __shared__ float Sred[4][3];
    __shared__ float Sfin[3];

    const int bid = blockIdx.x;            // = b*T + t
    const int tid = threadIdx.x;
    const long base_e = (long)bid * E_;
    const int  base_n = bid * N_;

    for (int i = tid; i < N_ * H_; i += 256) { mKey[i] = 0u; den[i] = 0.f; snum[i] = 0.f; }
    for (int i = tid; i < N_; i += 256) xs[i] = x[base_n + i];
    if (tid < H_) {
        int h = tid;
        float cl = 0.f, cr = 0.f, ce = 0.f;
        for (int f = 0; f < F_; ++f) {
            float wn = Wn[h * F_ + f];
            cl += wn * al[h * F_ + f];
            cr += wn * ar[h * F_ + f];
            ce += We[h * F_ + f] * ae[h * F_ + f];
        }
        coef[h] = cl; coef[3 + h] = cr; coef[6 + h] = ce;
    }
    __syncthreads();

    const float c0l = coef[0], c1l = coef[1], c2l = coef[2];
    const float c0r = coef[3], c1r = coef[4], c2r = coef[5];
    const float c0e = coef[6], c1e = coef[7], c2e = coef[8];

    // ---- pass 1: per-(dst,h) running max of leaky-relu'd logits ----
    for (int i = tid; i < E_; i += 256) {
        int s = src[i], d = dst[i];
        float w = ew[base_e + i];
        float xsv = xs[s], xdv = xs[d];
        float e0 = xsv * c0l + xdv * c0r + w * c0e; e0 = e0 > 0.f ? e0 : 0.2f * e0;
        float e1 = xsv * c1l + xdv * c1r + w * c1e; e1 = e1 > 0.f ? e1 : 0.2f * e1;
        float e2 = xsv * c2l + xdv * c2r + w * c2e; e2 = e2 > 0.f ? e2 : 0.2f * e2;
        atomicMax(&mKey[d * 3 + 0], fkey(e0));
        atomicMax(&mKey[d * 3 + 1], fkey(e1));
        atomicMax(&mKey[d * 3 + 2], fkey(e2));
    }
    __syncthreads();

    // ---- pass 2: denominator and x_src-weighted numerator sums ----
    for (int i = tid; i < E_; i += 256) {
        int s = src[i], d = dst[i];
        float w = ew[base_e + i];
        float xsv = xs[s], xdv = xs[d];
        float e0 = xsv * c0l + xdv * c0r + w * c0e; e0 = e0 > 0.f ? e0 : 0.2f * e0;
        float e1 = xsv * c1l + xdv * c1r + w * c1e; e1 = e1 > 0.f ? e1 : 0.2f * e1;
        float e2 = xsv * c2l + xdv * c2r + w * c2e; e2 = e2 > 0.f ? e2 : 0.2f * e2;
        float p0 = __expf(e0 - fdec(mKey[d * 3 + 0]));
        float p1 = __expf(e1 - fdec(mKey[d * 3 + 1]));
        float p2 = __expf(e2 - fdec(mKey[d * 3 + 2]));
        atomicAdd(&den[d * 3 + 0], p0);
        atomicAdd(&den[d * 3 + 1], p1);
        atomicAdd(&den[d * 3 + 2], p2);
        atomicAdd(&snum[d * 3 + 0], p0 * xsv);
        atomicAdd(&snum[d * 3 + 1], p1 * xsv);
        atomicAdd(&snum[d * 3 + 2], p2 * xsv);
    }
    __syncthreads();

    // ---- mean over nodes: S[h] = (1/N) * sum_n snum/den (empty nodes -> 0) ----
    float a0 = 0.f, a1 = 0.f, a2 = 0.f;
    for (int n = tid; n < N_; n += 256) {
        float d0 = den[n * 3 + 0]; if (d0 > 0.f) a0 += snum[n * 3 + 0] / d0;
        float d1 = den[n * 3 + 1]; if (d1 > 0.f) a1 += snum[n * 3 + 1] / d1;
        float d2 = den[n * 3 + 2]; if (d2 > 0.f) a2 += snum[n * 3 + 2] / d2;
    }
    for (int off = 32; off; off >>= 1) {
        a0 += __shfl_down(a0, off);
        a1 += __shfl_down(a1, off);
        a2 += __shfl_down(a2, off);
    }
    int wave = tid >> 6, lane = tid & 63;
    if (lane == 0) { Sred[wave][0] = a0; Sred[wave][1] = a1; Sred[wave][2] = a2; }
    __syncthreads();
    if (tid < 3) {
        float s = Sred[0][tid] + Sred[1][tid] + Sred[2][tid] + Sred[3][tid];
        Sfin[tid] = s * (1.0f / N_);
    }
    __syncthreads();
    if (tid < HF_) {
        int h = tid / F_;
        gru_in[bid * HF_ + tid] = Wn[tid] * Sfin[h] + gbias[tid];
    }
}

// ================= Kernel B: GRU over T steps, thread = (b, hidden unit) ================
__global__ __launch_bounds__(256) void gru_kernel(
    const float* __restrict__ gru_in, const float* __restrict__ Wih,
    const float* __restrict__ Whh, const float* __restrict__ bih,
    const float* __restrict__ bhh, float* __restrict__ h_out)
{
    __shared__ float sWih[48 * HF_];
    __shared__ float sWhh[48 * GRUH_];
    __shared__ float sbih[48], sbhh[48];
    __shared__ float hS[B_][GRUH_];
    __shared__ float xt[B_][HF_];

    const int tid = threadIdx.x;
    for (int i = tid; i < 48 * HF_; i += 256) sWih[i] = Wih[i];
    for (int i = tid; i < 48 * GRUH_; i += 256) sWhh[i] = Whh[i];
    if (tid < 48) { sbih[tid] = bih[tid]; sbhh[tid] = bhh[tid]; }
    const int b = tid >> 4, u = tid & 15;
    hS[b][u] = 0.f;
    __syncthreads();

    for (int t = 0; t < T_; ++t) {
        for (int i = tid; i < B_ * HF_; i += 256) {
            int bb = i / HF_, j = i % HF_;
            xt[bb][j] = gru_in[(bb * T_ + t) * HF_ + j];
        }
        __syncthreads();
        float gr = sbih[u], gz = sbih[16 + u], gn = sbih[32 + u];
        #pragma unroll
        for (int j = 0; j < HF_; ++j) {
            float xv = xt[b][j];
            gr += xv * sWih[u * HF_ + j];
            gz += xv * sWih[(16 + u) * HF_ + j];
            gn += xv * sWih[(32 + u) * HF_ + j];
        }
        float hr = sbhh[u], hz = sbhh[16 + u], hn = sbhh[32 + u];
        #pragma unroll
        for (int k = 0; k < GRUH_; ++k) {
            float hv = hS[b][k];
            hr += hv * sWhh[u * GRUH_ + k];
            hz += hv * sWhh[(16 + u) * GRUH_ + k];
            hn += hv * sWhh[(32 + u) * GRUH_ + k];
        }
        float r = 1.f / (1.f + __expf(-(gr + hr)));
        float z = 1.f / (1.f + __expf(-(gz + hz)));
        float n = tanhf(gn + r * hn);
        float hnew = (1.f - z) * n + z * hS[b][u];
        __syncthreads();
        hS[b][u] = hnew;
        __syncthreads();
    }
    h_out[b * GRUH_ + u] = hS[b][u];
}

// ================= Kernel C: FC  out[b,o] = h_n[b,:] . W_fc[o,:] + b_fc[o] ================
__global__ __launch_bounds__(256) void fc_kernel(
    const float* __restrict__ h_n, const float* __restrict__ Wfc,
    const float* __restrict__ bfc, float* __restrict__ out)
{
    int idx = blockIdx.x * 256 + threadIdx.x;
    if (idx >= B_ * OUTB_) return;
    int b = idx / OUTB_, o = idx % OUTB_;
    const float* wr = Wfc + (long)o * GRUH_;
    const float* hr = h_n + b * GRUH_;
    float acc = bfc[o];
    #pragma unroll
    for (int k = 0; k < GRUH_; ++k) acc += hr[k] * wr[k];
    out[idx] = acc;
}

extern "C" void kernel_launch(void* const* d_in, const int* in_sizes, int n_in,
                              void* d_out, int out_size, void* d_ws, size_t ws_size,
                              hipStream_t stream) {
    const float* x    = (const float*)d_in[0];
    const float* ew   = (const float*)d_in[1];
    const float* Wn   = (const float*)d_in[2];
    const float* We   = (const float*)d_in[3];
    const float* al   = (const float*)d_in[4];
    const float* ar   = (const float*)d_in[5];
    const float* ae   = (const float*)d_in[6];
    const float* gb   = (const float*)d_in[7];
    const float* Wih  = (const float*)d_in[8];
    const float* Whh  = (const float*)d_in[9];
    const float* bih  = (const float*)d_in[10];
    const float* bhh  = (const float*)d_in[11];
    const float* Wfc  = (const float*)d_in[12];
    const float* bfc  = (const float*)d_in[13];
    const int*   src  = (const int*)d_in[14];
    const int*   dst  = (const int*)d_in[15];
    float* out = (float*)d_out;

    float* gru_in = (float*)d_ws;                 // [B*T, 24]
    float* h_n    = gru_in + B_ * T_ * HF_;       // [B, 16]

    gat_kernel<<<B_ * T_, 256, 0, stream>>>(x, ew, Wn, We, al, ar, ae, gb, src, dst, gru_in);
    gru_kernel<<<1, 256, 0, stream>>>(gru_in, Wih, Whh, bih, bhh, h_n);
    fc_kernel<<<(B_ * OUTB_ + 255) / 256, 256, 0, stream>>>(h_n, Wfc, bfc, out);
}

// Round 2
// 83.042 us; speedup vs baseline: 2.6613x; 2.6613x over previous
//
#include <hip/hip_runtime.h>
#include <math.h>

#define B_ 16
#define T_ 24
#define N_ 300
#define E_ 9600
#define H_ 3
#define F_ 8
#define HF_ 24
#define GRUH_ 16
#define OUTB_ 7200   // NUM_AIRPORTS * HORIZON

// ================= Kernel S: CSR bucketing of the shared topology =================
// ws out: rp[N+1] (row ptr by dst), eid[E] (orig edge id sorted by dst), esrc[E] (src, u16)
__global__ __launch_bounds__(256) void sort_kernel(
    const int* __restrict__ src, const int* __restrict__ dst,
    int* __restrict__ rp, int* __restrict__ eid, unsigned short* __restrict__ esrc)
{
    __shared__ int cnt[N_];
    __shared__ int off[N_];
    const int tid = threadIdx.x;
    for (int i = tid; i < N_; i += 256) cnt[i] = 0;
    __syncthreads();
    for (int i = tid; i < E_; i += 256) atomicAdd(&cnt[dst[i]], 1);
    __syncthreads();
    if (tid == 0) {
        int run = 0;
        for (int n = 0; n < N_; ++n) { off[n] = run; rp[n] = run; run += cnt[n]; }
        rp[N_] = run;
    }
    __syncthreads();
    for (int i = tid; i < E_; i += 256) {
        int d = dst[i];
        int pos = atomicAdd(&off[d], 1);
        eid[pos] = i;
        esrc[pos] = (unsigned short)src[i];
    }
}

// ================= Kernel A: EdgeGAT + mean-pool + gi precompute, block per (b,t) ====
__global__ __launch_bounds__(256) void gat_kernel(
    const float* __restrict__ x, const float* __restrict__ ew,
    const float* __restrict__ Wn, const float* __restrict__ We,
    const float* __restrict__ al, const float* __restrict__ ar,
    const float* __restrict__ ae, const float* __restrict__ gbias,
    const int* __restrict__ rp_g, const int* __restrict__ eid_g,
    const unsigned short* __restrict__ esrc_g,
    const float* __restrict__ Wih, const float* __restrict__ bih,
    float* __restrict__ gi_out)
{
    __shared__ float ews_s[E_];            // edge weights in dst-sorted order
    __shared__ unsigned short esrc_l[E_];  // src node per sorted edge
    __shared__ float xs[N_];
    __shared__ int rp_l[N_ + 1];
    __shared__ float coef[9];
    __shared__ float Sred[4][3];
    __shared__ float Sfin[3];
    __shared__ float gval[HF_];

    const int bid = blockIdx.x;            // = b*T + t
    const int tid = threadIdx.x;
    const long base_e = (long)bid * E_;
    const int  base_n = bid * N_;

    for (int i = tid; i < N_; i += 256) xs[i] = x[base_n + i];
    for (int i = tid; i <= N_; i += 256) rp_l[i] = rp_g[i];
    for (int p = tid; p < E_; p += 256) {
        int e = eid_g[p];
        ews_s[p] = ew[base_e + e];
        esrc_l[p] = esrc_g[p];
    }
    if (tid < H_) {
        int h = tid;
        float cl = 0.f, cr = 0.f, ce = 0.f;
        for (int f = 0; f < F_; ++f) {
            float wn = Wn[h * F_ + f];
            cl += wn * al[h * F_ + f];
            cr += wn * ar[h * F_ + f];
            ce += We[h * F_ + f] * ae[h * F_ + f];
        }
        coef[h] = cl; coef[3 + h] = cr; coef[6 + h] = ce;
    }
    __syncthreads();

    // ---- per-(node,head) softmax-weighted sum, NO atomics, no max pass (|e| < ~1) ----
    float acc[3];
    #pragma unroll
    for (int h = 0; h < H_; ++h) {
        const float cl = coef[h], cr = coef[3 + h], ce = coef[6 + h];
        float a = 0.f;
        for (int n = tid; n < N_; n += 256) {
            const int p0 = rp_l[n], p1 = rp_l[n + 1];
            const float xd = xs[n];
            float num = 0.f, den = 0.f;
            for (int p = p0; p < p1; ++p) {
                float w = ews_s[p];
                float xsv = xs[esrc_l[p]];
                float e = xsv * cl + xd * cr + w * ce;
                e = e > 0.f ? e : 0.2f * e;
                float pe = __expf(e);
                den += pe;
                num += pe * xsv;
            }
            if (den > 0.f) a += num / den;
        }
        acc[h] = a;
    }

    // ---- block reduction of acc -> S[h] ----
    float a0 = acc[0], a1 = acc[1], a2 = acc[2];
    for (int off = 32; off; off >>= 1) {
        a0 += __shfl_down(a0, off);
        a1 += __shfl_down(a1, off);
        a2 += __shfl_down(a2, off);
    }
    int wave = tid >> 6, lane = tid & 63;
    if (lane == 0) { Sred[wave][0] = a0; Sred[wave][1] = a1; Sred[wave][2] = a2; }
    __syncthreads();
    if (tid < 3) {
        float s = Sred[0][tid] + Sred[1][tid] + Sred[2][tid] + Sred[3][tid];
        Sfin[tid] = s * (1.0f / N_);
    }
    __syncthreads();
    // gru_in[k] = Wn[k]*S[k/8] + gbias[k]
    if (tid < HF_) gval[tid] = Wn[tid] * Sfin[tid / F_] + gbias[tid];
    __syncthreads();
    // gi[j] = bih[j] + sum_k Wih[j,k]*gru_in[k]   (input-side GRU gates, all precomputable)
    if (tid < 48) {
        float g = bih[tid];
        #pragma unroll
        for (int k = 0; k < HF_; ++k) g += Wih[tid * HF_ + k] * gval[k];
        gi_out[bid * 48 + tid] = g;
    }
}

// ================= Kernel B: GRU recurrence, shuffle-only, h in registers ============
// 256 threads = 4 waves; each wave holds 4 batches (16 lanes each). No __syncthreads.
__global__ __launch_bounds__(256) void gru_kernel(
    const float* __restrict__ gi, const float* __restrict__ Whh,
    const float* __restrict__ bhh, float* __restrict__ h_out)
{
    const int tid = threadIdx.x;
    const int l = tid & 63;
    const int u = l & 15;              // hidden unit
    const int bg = l & 48;             // base lane of this batch's 16-lane group
    const int b = (tid >> 6) * 4 + (l >> 4);

    float whr[GRUH_], whz[GRUH_], whn[GRUH_];
    #pragma unroll
    for (int k = 0; k < GRUH_; ++k) {
        whr[k] = Whh[u * GRUH_ + k];
        whz[k] = Whh[(16 + u) * GRUH_ + k];
        whn[k] = Whh[(32 + u) * GRUH_ + k];
    }
    const float bhr = bhh[u], bhz = bhh[16 + u], bhn = bhh[32 + u];

    float h = 0.f;
    for (int t = 0; t < T_; ++t) {
        const float* g = gi + (b * T_ + t) * 48;
        float gr = g[u], gz = g[16 + u], gn = g[32 + u];
        float hr = bhr, hz = bhz, hn = bhn;
        #pragma unroll
        for (int k = 0; k < GRUH_; ++k) {
            float hk = __shfl(h, bg + k, 64);
            hr += whr[k] * hk;
            hz += whz[k] * hk;
            hn += whn[k] * hk;
        }
        float r = 1.f / (1.f + __expf(-(gr + hr)));
        float z = 1.f / (1.f + __expf(-(gz + hz)));
        float n = tanhf(gn + r * hn);
        h = (1.f - z) * n + z * h;
    }
    h_out[b * GRUH_ + u] = h;
}

// ================= Kernel C: FC  out[b,o] = h_n[b,:] . W_fc[o,:] + b_fc[o] ===========
__global__ __launch_bounds__(256) void fc_kernel(
    const float* __restrict__ h_n, const float* __restrict__ Wfc,
    const float* __restrict__ bfc, float* __restrict__ out)
{
    int idx = blockIdx.x * 256 + threadIdx.x;
    if (idx >= B_ * OUTB_) return;
    int b = idx / OUTB_, o = idx % OUTB_;
    const float* wr = Wfc + (long)o * GRUH_;
    const float* hr = h_n + b * GRUH_;
    float acc = bfc[o];
    #pragma unroll
    for (int k = 0; k < GRUH_; ++k) acc += hr[k] * wr[k];
    out[idx] = acc;
}

extern "C" void kernel_launch(void* const* d_in, const int* in_sizes, int n_in,
                              void* d_out, int out_size, void* d_ws, size_t ws_size,
                              hipStream_t stream) {
    const float* x    = (const float*)d_in[0];
    const float* ew   = (const float*)d_in[1];
    const float* Wn   = (const float*)d_in[2];
    const float* We   = (const float*)d_in[3];
    const float* al   = (const float*)d_in[4];
    const float* ar   = (const float*)d_in[5];
    const float* ae   = (const float*)d_in[6];
    const float* gb   = (const float*)d_in[7];
    const float* Wih  = (const float*)d_in[8];
    const float* Whh  = (const float*)d_in[9];
    const float* bih  = (const float*)d_in[10];
    const float* bhh  = (const float*)d_in[11];
    const float* Wfc  = (const float*)d_in[12];
    const float* bfc  = (const float*)d_in[13];
    const int*   src  = (const int*)d_in[14];
    const int*   dst  = (const int*)d_in[15];
    float* out = (float*)d_out;

    // ws layout
    int* rp = (int*)d_ws;                              // [301]
    int* eid = rp + 304;                               // [9600]
    unsigned short* esrc = (unsigned short*)(eid + E_);// [9600]
    float* gi = (float*)(esrc + E_);                   // [384*48]
    float* h_n = gi + B_ * T_ * 48;                    // [16*16]

    sort_kernel<<<1, 256, 0, stream>>>(src, dst, rp, eid, esrc);
    gat_kernel<<<B_ * T_, 256, 0, stream>>>(x, ew, Wn, We, al, ar, ae, gb,
                                            rp, eid, esrc, Wih, bih, gi);
    gru_kernel<<<1, 256, 0, stream>>>(gi, Whh, bhh, h_n);
    fc_kernel<<<(B_ * OUTB_ + 255) / 256, 256, 0, stream>>>(h_n, Wfc, bfc, out);
}